// Round 1
// baseline (1954.376 us; speedup 1.0000x reference)
//
#include <hip/hip_runtime.h>
#include <math.h>

#define H  128
#define NN 50000
#define EE 800000
#define GG 256

#define XPAD 276   // LDS row stride for edge x-tile (268 cols, padded, mult of 4)
#define NPAD 260   // LDS row stride for node x-tile (256 cols)
#define EPAD 132   // LDS row stride for hidden tile (128 cols)

__device__ __forceinline__ float silu_f(float x) {
    return x / (1.0f + __expf(-x));
}

// lattice_ips[g][i][k] = dot(L[g][i,:], L[g][k,:])
__global__ void lat_kernel(const float* __restrict__ lat, float* __restrict__ latg) {
    int idx = blockIdx.x * blockDim.x + threadIdx.x;
    if (idx >= GG * 9) return;
    int g = idx / 9, r = idx % 9;
    int i = r / 3, k = r % 3;
    const float* L = lat + g * 9;
    latg[idx] = L[i*3+0]*L[k*3+0] + L[i*3+1]*L[k*3+1] + L[i*3+2]*L[k*3+2];
}

__global__ void count_kernel(const int* __restrict__ ei, float* __restrict__ cnt) {
    int e = blockIdx.x * blockDim.x + threadIdx.x;
    if (e < EE) atomicAdd(&cnt[ei[EE + e]], 1.0f);
}

__global__ __launch_bounds__(256) void edge_kernel(
    const float* __restrict__ nf, const float* __restrict__ latg,
    const float* __restrict__ fd,
    const float* __restrict__ W1, const float* __restrict__ b1,
    const float* __restrict__ W2, const float* __restrict__ b2,
    const int* __restrict__ ei, const int* __restrict__ e2g,
    float* __restrict__ out_edge, float* __restrict__ sums)
{
    __shared__ float x_lds[32][XPAD];   // 35.3 KB; later overlaid as e1[32][EPAD]
    __shared__ int sIdx[96];            // src[32], dst[32], g[32]
    int tid = threadIdx.x;
    int eb = blockIdx.x * 32;

    if (tid < 96) {
        int w = tid >> 5, l = tid & 31;
        int e = eb + l;
        int v = (w == 0) ? ei[e] : (w == 1) ? ei[EE + e] : e2g[e];
        sIdx[tid] = v;
    }
    __syncthreads();

    // stage x[e][0:268] = [hi(128) | hj(128) | lat(9) | fd(3)], in float4 chunks
    for (int idx = tid; idx < 67 * 32; idx += 256) {
        int e = idx & 31, c = idx >> 5;
        float4 v;
        if (c < 32) {
            v = *(const float4*)(nf + (size_t)sIdx[e] * H + 4 * c);
        } else if (c < 64) {
            v = *(const float4*)(nf + (size_t)sIdx[32 + e] * H + 4 * (c - 32));
        } else {
            int g = sIdx[64 + e];
            float t[4];
            #pragma unroll
            for (int q = 0; q < 4; ++q) {
                int k = 4 * c + q;   // 256..267
                t[q] = (k < 265) ? latg[g * 9 + (k - 256)]
                                 : fd[(size_t)(eb + e) * 3 + (k - 265)];
            }
            v = make_float4(t[0], t[1], t[2], t[3]);
        }
        *(float4*)(&x_lds[e][4 * c]) = v;
    }
    __syncthreads();

    int tj = tid & 31, te = tid >> 5;
    int j0 = tj * 4, e0 = te * 4;

    // ---- matmul1: [32,268] @ W1[268,128] ----
    float acc[4][4];
    #pragma unroll
    for (int a = 0; a < 4; ++a)
        #pragma unroll
        for (int b = 0; b < 4; ++b) acc[a][b] = 0.0f;

    for (int k4 = 0; k4 < 67; ++k4) {
        float4 xv[4];
        #pragma unroll
        for (int ee = 0; ee < 4; ++ee)
            xv[ee] = *(const float4*)(&x_lds[e0 + ee][4 * k4]);
        float4 wv[4];
        #pragma unroll
        for (int q = 0; q < 4; ++q)
            wv[q] = *(const float4*)(W1 + (size_t)(4 * k4 + q) * H + j0);
        #pragma unroll
        for (int ee = 0; ee < 4; ++ee) {
            const float* xs = (const float*)&xv[ee];
            #pragma unroll
            for (int q = 0; q < 4; ++q) {
                float x = xs[q];
                acc[ee][0] = fmaf(x, wv[q].x, acc[ee][0]);
                acc[ee][1] = fmaf(x, wv[q].y, acc[ee][1]);
                acc[ee][2] = fmaf(x, wv[q].z, acc[ee][2]);
                acc[ee][3] = fmaf(x, wv[q].w, acc[ee][3]);
            }
        }
    }

    float4 b1v = *(const float4*)(b1 + j0);
    __syncthreads();                 // everyone done reading x_lds
    float* e1_lds = &x_lds[0][0];    // overlay [32][EPAD]
    #pragma unroll
    for (int ee = 0; ee < 4; ++ee) {
        float4 r;
        r.x = silu_f(acc[ee][0] + b1v.x);
        r.y = silu_f(acc[ee][1] + b1v.y);
        r.z = silu_f(acc[ee][2] + b1v.z);
        r.w = silu_f(acc[ee][3] + b1v.w);
        *(float4*)(e1_lds + (size_t)(e0 + ee) * EPAD + j0) = r;
    }
    __syncthreads();

    // ---- matmul2: [32,128] @ W2[128,128] ----
    float acc2[4][4];
    #pragma unroll
    for (int a = 0; a < 4; ++a)
        #pragma unroll
        for (int b = 0; b < 4; ++b) acc2[a][b] = 0.0f;

    for (int k4 = 0; k4 < 32; ++k4) {
        float4 xv[4];
        #pragma unroll
        for (int ee = 0; ee < 4; ++ee)
            xv[ee] = *(const float4*)(e1_lds + (size_t)(e0 + ee) * EPAD + 4 * k4);
        float4 wv[4];
        #pragma unroll
        for (int q = 0; q < 4; ++q)
            wv[q] = *(const float4*)(W2 + (size_t)(4 * k4 + q) * H + j0);
        #pragma unroll
        for (int ee = 0; ee < 4; ++ee) {
            const float* xs = (const float*)&xv[ee];
            #pragma unroll
            for (int q = 0; q < 4; ++q) {
                float x = xs[q];
                acc2[ee][0] = fmaf(x, wv[q].x, acc2[ee][0]);
                acc2[ee][1] = fmaf(x, wv[q].y, acc2[ee][1]);
                acc2[ee][2] = fmaf(x, wv[q].z, acc2[ee][2]);
                acc2[ee][3] = fmaf(x, wv[q].w, acc2[ee][3]);
            }
        }
    }

    float4 b2v = *(const float4*)(b2 + j0);
    #pragma unroll
    for (int ee = 0; ee < 4; ++ee) {
        float4 r;
        r.x = silu_f(acc2[ee][0] + b2v.x);
        r.y = silu_f(acc2[ee][1] + b2v.y);
        r.z = silu_f(acc2[ee][2] + b2v.z);
        r.w = silu_f(acc2[ee][3] + b2v.w);
        int e = eb + e0 + ee;
        *(float4*)(out_edge + (size_t)e * H + j0) = r;
        int d = sIdx[32 + e0 + ee];
        float* srow = sums + (size_t)d * H + j0;
        atomicAdd(srow + 0, r.x);
        atomicAdd(srow + 1, r.y);
        atomicAdd(srow + 2, r.z);
        atomicAdd(srow + 3, r.w);
    }
}

__global__ __launch_bounds__(256) void node_kernel(
    const float* __restrict__ nf, const float* __restrict__ sums,
    const float* __restrict__ cnt,
    const float* __restrict__ W3, const float* __restrict__ b3,
    const float* __restrict__ W4, const float* __restrict__ b4,
    float* __restrict__ out0)
{
    __shared__ float x_lds[32][NPAD];   // 33.3 KB; overlaid as m[32][EPAD]
    int tid = threadIdx.x;
    int nb = blockIdx.x * 32;

    // stage x[n][0:256] = [nf(128) | agg(128)]
    for (int idx = tid; idx < 64 * 32; idx += 256) {
        int n = idx & 31, c = idx >> 5;
        int node = nb + n;
        float4 v = make_float4(0.f, 0.f, 0.f, 0.f);
        if (node < NN) {
            if (c < 32) {
                v = *(const float4*)(nf + (size_t)node * H + 4 * c);
            } else {
                float4 s = *(const float4*)(sums + (size_t)node * H + 4 * (c - 32));
                float inv = 1.0f / fmaxf(cnt[node], 1.0f);
                v = make_float4(s.x * inv, s.y * inv, s.z * inv, s.w * inv);
            }
        }
        *(float4*)(&x_lds[n][4 * c]) = v;
    }
    __syncthreads();

    int tj = tid & 31, te = tid >> 5;
    int j0 = tj * 4, n0 = te * 4;

    // ---- matmul3: [32,256] @ W3[256,128] ----
    float acc[4][4];
    #pragma unroll
    for (int a = 0; a < 4; ++a)
        #pragma unroll
        for (int b = 0; b < 4; ++b) acc[a][b] = 0.0f;

    for (int k4 = 0; k4 < 64; ++k4) {
        float4 xv[4];
        #pragma unroll
        for (int ee = 0; ee < 4; ++ee)
            xv[ee] = *(const float4*)(&x_lds[n0 + ee][4 * k4]);
        float4 wv[4];
        #pragma unroll
        for (int q = 0; q < 4; ++q)
            wv[q] = *(const float4*)(W3 + (size_t)(4 * k4 + q) * H + j0);
        #pragma unroll
        for (int ee = 0; ee < 4; ++ee) {
            const float* xs = (const float*)&xv[ee];
            #pragma unroll
            for (int q = 0; q < 4; ++q) {
                float x = xs[q];
                acc[ee][0] = fmaf(x, wv[q].x, acc[ee][0]);
                acc[ee][1] = fmaf(x, wv[q].y, acc[ee][1]);
                acc[ee][2] = fmaf(x, wv[q].z, acc[ee][2]);
                acc[ee][3] = fmaf(x, wv[q].w, acc[ee][3]);
            }
        }
    }

    float4 b3v = *(const float4*)(b3 + j0);
    __syncthreads();
    float* m_lds = &x_lds[0][0];   // overlay [32][EPAD]
    #pragma unroll
    for (int ee = 0; ee < 4; ++ee) {
        float4 r;
        r.x = silu_f(acc[ee][0] + b3v.x);
        r.y = silu_f(acc[ee][1] + b3v.y);
        r.z = silu_f(acc[ee][2] + b3v.z);
        r.w = silu_f(acc[ee][3] + b3v.w);
        *(float4*)(m_lds + (size_t)(n0 + ee) * EPAD + j0) = r;
    }
    __syncthreads();

    // ---- matmul4: [32,128] @ W4[128,128] ----
    float acc2[4][4];
    #pragma unroll
    for (int a = 0; a < 4; ++a)
        #pragma unroll
        for (int b = 0; b < 4; ++b) acc2[a][b] = 0.0f;

    for (int k4 = 0; k4 < 32; ++k4) {
        float4 xv[4];
        #pragma unroll
        for (int ee = 0; ee < 4; ++ee)
            xv[ee] = *(const float4*)(m_lds + (size_t)(n0 + ee) * EPAD + 4 * k4);
        float4 wv[4];
        #pragma unroll
        for (int q = 0; q < 4; ++q)
            wv[q] = *(const float4*)(W4 + (size_t)(4 * k4 + q) * H + j0);
        #pragma unroll
        for (int ee = 0; ee < 4; ++ee) {
            const float* xs = (const float*)&xv[ee];
            #pragma unroll
            for (int q = 0; q < 4; ++q) {
                float x = xs[q];
                acc2[ee][0] = fmaf(x, wv[q].x, acc2[ee][0]);
                acc2[ee][1] = fmaf(x, wv[q].y, acc2[ee][1]);
                acc2[ee][2] = fmaf(x, wv[q].z, acc2[ee][2]);
                acc2[ee][3] = fmaf(x, wv[q].w, acc2[ee][3]);
            }
        }
    }

    float4 b4v = *(const float4*)(b4 + j0);
    #pragma unroll
    for (int ee = 0; ee < 4; ++ee) {
        int node = nb + n0 + ee;
        if (node < NN) {
            float4 base = *(const float4*)(nf + (size_t)node * H + j0);
            float4 r;
            r.x = base.x + silu_f(acc2[ee][0] + b4v.x);
            r.y = base.y + silu_f(acc2[ee][1] + b4v.y);
            r.z = base.z + silu_f(acc2[ee][2] + b4v.z);
            r.w = base.w + silu_f(acc2[ee][3] + b4v.w);
            *(float4*)(out0 + (size_t)node * H + j0) = r;
        }
    }
}

extern "C" void kernel_launch(void* const* d_in, const int* in_sizes, int n_in,
                              void* d_out, int out_size, void* d_ws, size_t ws_size,
                              hipStream_t stream) {
    const float* nf  = (const float*)d_in[0];
    // d_in[1] frac_coords: unused by the reference
    const float* lat = (const float*)d_in[2];
    const float* fd  = (const float*)d_in[3];
    const float* W1  = (const float*)d_in[4];
    const float* b1  = (const float*)d_in[5];
    const float* W2  = (const float*)d_in[6];
    const float* b2  = (const float*)d_in[7];
    const float* W3  = (const float*)d_in[8];
    const float* b3  = (const float*)d_in[9];
    const float* W4  = (const float*)d_in[10];
    const float* b4  = (const float*)d_in[11];
    const int* ei    = (const int*)d_in[12];   // src = ei[0:E], dst = ei[E:2E]
    const int* e2g   = (const int*)d_in[13];

    float* out0     = (float*)d_out;                        // [N,H]
    float* out_edge = (float*)d_out + (size_t)NN * H;       // [E,H]

    char* ws = (char*)d_ws;
    float* sums = (float*)ws;                                   // [N,H]
    float* cnt  = (float*)(ws + (size_t)NN * H * 4);            // [N]
    float* latg = (float*)(ws + (size_t)NN * H * 4 + (size_t)NN * 4); // [G,9]

    hipMemsetAsync(sums, 0, (size_t)NN * H * 4 + (size_t)NN * 4, stream);

    lat_kernel<<<(GG * 9 + 255) / 256, 256, 0, stream>>>(lat, latg);
    count_kernel<<<(EE + 255) / 256, 256, 0, stream>>>(ei, cnt);
    edge_kernel<<<EE / 32, 256, 0, stream>>>(nf, latg, fd, W1, b1, W2, b2,
                                             ei, e2g, out_edge, sums);
    node_kernel<<<(NN + 31) / 32, 256, 0, stream>>>(nf, sums, cnt, W3, b3, W4, b4, out0);
}

// Round 3
// 568.154 us; speedup vs baseline: 3.4399x; 3.4399x over previous
//
#include <hip/hip_runtime.h>
#include <hip/hip_bf16.h>
#include <math.h>

#define H  128
#define NN 50000
#define EE 800000
#define GG 256

#define K1 288          // padded 268 -> 288 (9 k-steps of 32)
#define K3 256
#define XSTRIDE 296     // edge x-tile LDS row stride (bf16 elems)
#define NSTRIDE 264     // node x-tile LDS row stride
#define ESTRIDE 136     // hidden tile LDS row stride

typedef __attribute__((ext_vector_type(8))) short bhalf8;
typedef __attribute__((ext_vector_type(4))) float f32x4;

__device__ __forceinline__ float silu_f(float x) {
    return x / (1.0f + __expf(-x));
}

// fp32 -> bf16 with round-to-nearest-even (header-independent)
__device__ __forceinline__ unsigned short f2bf(float x) {
    unsigned int u = __float_as_uint(x);
    unsigned int r = 0x7fffu + ((u >> 16) & 1u);
    return (unsigned short)((u + r) >> 16);
}

// ---- prep kernels ----

// node_features fp32 -> bf16
__global__ void cvt_nf_kernel(const float* __restrict__ nf, unsigned short* __restrict__ nfb) {
    int idx = blockIdx.x * blockDim.x + threadIdx.x;   // one float4 per thread
    if (idx >= NN * H / 4) return;
    float4 v = *(const float4*)(nf + (size_t)idx * 4);
    ushort4 o;
    o.x = f2bf(v.x); o.y = f2bf(v.y); o.z = f2bf(v.z); o.w = f2bf(v.w);
    *(ushort4*)(nfb + (size_t)idx * 4) = o;
}

// W [K][128] fp32 -> WT [128][Kpad] bf16 (zero-padded rows K..Kpad)
__global__ void transpose_w_kernel(const float* __restrict__ W, unsigned short* __restrict__ WT,
                                   int K, int Kpad) {
    int k = blockIdx.x * blockDim.x + threadIdx.x;
    int c = blockIdx.y;
    if (k >= Kpad) return;
    WT[(size_t)c * Kpad + k] = (k < K) ? f2bf(W[(size_t)k * H + c]) : (unsigned short)0;
}

// lattice_ips -> bf16 [G][16] (9 values + zero pad)
__global__ void lat_kernel(const float* __restrict__ lat, unsigned short* __restrict__ latg) {
    int idx = blockIdx.x * blockDim.x + threadIdx.x;
    if (idx >= GG * 16) return;
    int g = idx >> 4, r = idx & 15;
    float v = 0.0f;
    if (r < 9) {
        int i = r / 3, k = r % 3;
        const float* L = lat + g * 9;
        v = L[i*3+0]*L[k*3+0] + L[i*3+1]*L[k*3+1] + L[i*3+2]*L[k*3+2];
    }
    latg[idx] = f2bf(v);
}

__global__ void count_kernel(const int* __restrict__ ei, float* __restrict__ cnt) {
    int e = blockIdx.x * blockDim.x + threadIdx.x;
    if (e < EE) atomicAdd(&cnt[ei[EE + e]], 1.0f);
}

// ---- edge kernel: 64 edges x 128 cols per block, 4 waves (2x2) ----
__global__ __launch_bounds__(256) void edge_kernel(
    const unsigned short* __restrict__ nfb, const unsigned short* __restrict__ latg,
    const float* __restrict__ fd,
    const unsigned short* __restrict__ W1T, const float* __restrict__ b1,
    const unsigned short* __restrict__ W2T, const float* __restrict__ b2,
    const int* __restrict__ ei, const int* __restrict__ e2g,
    float* __restrict__ out_edge, float* __restrict__ sums)
{
    __shared__ unsigned short x_lds[64 * XSTRIDE];   // 37.9 KB; overlaid as e1[64][ESTRIDE]
    __shared__ int sSrc[64], sDst[64], sG[64];

    int tid = threadIdx.x;
    int eb = blockIdx.x * 64;

    if (tid < 64)       sSrc[tid]       = ei[eb + tid];
    else if (tid < 128) sDst[tid - 64]  = ei[EE + eb + (tid - 64)];
    else if (tid < 192) sG[tid - 128]   = e2g[eb + (tid - 128)];
    __syncthreads();

    // stage hi|hj: 64 rows x 32 chunks of 8 bf16 (cols 0..255)
    #pragma unroll
    for (int p = 0; p < 8; ++p) {
        int idx = p * 256 + tid;
        int e = idx >> 5, c = idx & 31;
        int node = (c < 16) ? sSrc[e] : sDst[e];
        int cc = c & 15;
        uint4 v = *(const uint4*)(nfb + (size_t)node * H + cc * 8);
        // dest cols: c<16 -> hi at c*8; c>=16 -> hj at 128+(c-16)*8 == c*8
        *(uint4*)(&x_lds[e * XSTRIDE + c * 8]) = v;
    }
    // tail cols 256..287: lat(9) fd(3) zeros(20)
    if (tid < 64) {
        int e = tid, g = sG[e];
        unsigned short t[16];
        #pragma unroll
        for (int q = 0; q < 9; ++q) t[q] = latg[g * 16 + q];
        #pragma unroll
        for (int q = 0; q < 3; ++q) t[9 + q] = f2bf(fd[(size_t)(eb + e) * 3 + q]);
        #pragma unroll
        for (int q = 12; q < 16; ++q) t[q] = 0;
        *(uint4*)(&x_lds[e * XSTRIDE + 256]) = ((uint4*)t)[0];
        *(uint4*)(&x_lds[e * XSTRIDE + 264]) = ((uint4*)t)[1];
        uint4 z; z.x = z.y = z.z = z.w = 0;
        *(uint4*)(&x_lds[e * XSTRIDE + 272]) = z;
        *(uint4*)(&x_lds[e * XSTRIDE + 280]) = z;
    }
    __syncthreads();

    int wid = tid >> 6, lane = tid & 63;
    int wr = wid >> 1, wc = wid & 1;       // wave tile: rows wr*32+.., cols wc*64+..
    int lr = lane & 15, lk = lane >> 4;    // lr: row/col in frag; lk: k-group 0..3

    // ---- mm1: x[64,288] @ W1T -> e1 ----
    f32x4 acc[2][4];
    #pragma unroll
    for (int m = 0; m < 2; ++m)
        #pragma unroll
        for (int n = 0; n < 4; ++n) acc[m][n] = (f32x4){0.f, 0.f, 0.f, 0.f};

    for (int ks = 0; ks < 9; ++ks) {
        bhalf8 a[2], b[4];
        #pragma unroll
        for (int m = 0; m < 2; ++m)
            a[m] = *(const bhalf8*)(&x_lds[(wr * 32 + m * 16 + lr) * XSTRIDE + ks * 32 + lk * 8]);
        #pragma unroll
        for (int n = 0; n < 4; ++n)
            b[n] = *(const bhalf8*)(W1T + (size_t)(wc * 64 + n * 16 + lr) * K1 + ks * 32 + lk * 8);
        #pragma unroll
        for (int m = 0; m < 2; ++m)
            #pragma unroll
            for (int n = 0; n < 4; ++n)
                acc[m][n] = __builtin_amdgcn_mfma_f32_16x16x32_bf16(a[m], b[n], acc[m][n], 0, 0, 0);
    }

    float bn1[4];
    #pragma unroll
    for (int n = 0; n < 4; ++n) bn1[n] = b1[wc * 64 + n * 16 + lr];

    __syncthreads();   // all waves done reading x_lds
    unsigned short* e1 = x_lds;   // overlay [64][ESTRIDE]
    #pragma unroll
    for (int m = 0; m < 2; ++m)
        #pragma unroll
        for (int n = 0; n < 4; ++n)
            #pragma unroll
            for (int j = 0; j < 4; ++j) {
                int row = wr * 32 + m * 16 + lk * 4 + j;
                int col = wc * 64 + n * 16 + lr;
                e1[row * ESTRIDE + col] = f2bf(silu_f(acc[m][n][j] + bn1[n]));
            }
    __syncthreads();

    // ---- mm2: e1[64,128] @ W2T ----
    f32x4 acc2[2][4];
    #pragma unroll
    for (int m = 0; m < 2; ++m)
        #pragma unroll
        for (int n = 0; n < 4; ++n) acc2[m][n] = (f32x4){0.f, 0.f, 0.f, 0.f};

    #pragma unroll
    for (int ks = 0; ks < 4; ++ks) {
        bhalf8 a[2], b[4];
        #pragma unroll
        for (int m = 0; m < 2; ++m)
            a[m] = *(const bhalf8*)(&e1[(wr * 32 + m * 16 + lr) * ESTRIDE + ks * 32 + lk * 8]);
        #pragma unroll
        for (int n = 0; n < 4; ++n)
            b[n] = *(const bhalf8*)(W2T + (size_t)(wc * 64 + n * 16 + lr) * H + ks * 32 + lk * 8);
        #pragma unroll
        for (int m = 0; m < 2; ++m)
            #pragma unroll
            for (int n = 0; n < 4; ++n)
                acc2[m][n] = __builtin_amdgcn_mfma_f32_16x16x32_bf16(a[m], b[n], acc2[m][n], 0, 0, 0);
    }

    float bn2[4];
    #pragma unroll
    for (int n = 0; n < 4; ++n) bn2[n] = b2[wc * 64 + n * 16 + lr];

    #pragma unroll
    for (int m = 0; m < 2; ++m)
        #pragma unroll
        for (int n = 0; n < 4; ++n)
            #pragma unroll
            for (int j = 0; j < 4; ++j) {
                int row = wr * 32 + m * 16 + lk * 4 + j;
                int col = wc * 64 + n * 16 + lr;
                float v = silu_f(acc2[m][n][j] + bn2[n]);
                out_edge[(size_t)(eb + row) * H + col] = v;
                atomicAdd(&sums[(size_t)sDst[row] * H + col], v);
            }
}

// ---- node kernel: 64 nodes x 128 cols per block ----
__global__ __launch_bounds__(256) void node_kernel(
    const float* __restrict__ nf, const unsigned short* __restrict__ nfb,
    const float* __restrict__ sums, const float* __restrict__ cnt,
    const unsigned short* __restrict__ W3T, const float* __restrict__ b3,
    const unsigned short* __restrict__ W4T, const float* __restrict__ b4,
    float* __restrict__ out0)
{
    __shared__ unsigned short x_lds[64 * NSTRIDE];   // 33.8 KB; overlaid as m[64][ESTRIDE]
    int tid = threadIdx.x;
    int nb = blockIdx.x * 64;

    // cols 0..127: nf bf16
    #pragma unroll
    for (int p = 0; p < 4; ++p) {
        int idx = p * 256 + tid;
        int n = idx >> 4, c = idx & 15;
        int node = nb + n; if (node >= NN) node = NN - 1;
        uint4 v = *(const uint4*)(nfb + (size_t)node * H + c * 8);
        *(uint4*)(&x_lds[n * NSTRIDE + c * 8]) = v;
    }
    // cols 128..255: agg = sums/max(cnt,1)
    #pragma unroll
    for (int p = 0; p < 8; ++p) {
        int idx = p * 256 + tid;
        int n = idx >> 5, c = idx & 31;
        int node = nb + n; if (node >= NN) node = NN - 1;
        float4 s = *(const float4*)(sums + (size_t)node * H + c * 4);
        float inv = 1.0f / fmaxf(cnt[node], 1.0f);
        ushort4 o;
        o.x = f2bf(s.x * inv); o.y = f2bf(s.y * inv);
        o.z = f2bf(s.z * inv); o.w = f2bf(s.w * inv);
        *(ushort4*)(&x_lds[n * NSTRIDE + 128 + c * 4]) = o;
    }
    __syncthreads();

    int wid = tid >> 6, lane = tid & 63;
    int wr = wid >> 1, wc = wid & 1;
    int lr = lane & 15, lk = lane >> 4;

    // ---- mm3: x[64,256] @ W3T ----
    f32x4 acc[2][4];
    #pragma unroll
    for (int m = 0; m < 2; ++m)
        #pragma unroll
        for (int n = 0; n < 4; ++n) acc[m][n] = (f32x4){0.f, 0.f, 0.f, 0.f};

    #pragma unroll
    for (int ks = 0; ks < 8; ++ks) {
        bhalf8 a[2], b[4];
        #pragma unroll
        for (int m = 0; m < 2; ++m)
            a[m] = *(const bhalf8*)(&x_lds[(wr * 32 + m * 16 + lr) * NSTRIDE + ks * 32 + lk * 8]);
        #pragma unroll
        for (int n = 0; n < 4; ++n)
            b[n] = *(const bhalf8*)(W3T + (size_t)(wc * 64 + n * 16 + lr) * K3 + ks * 32 + lk * 8);
        #pragma unroll
        for (int m = 0; m < 2; ++m)
            #pragma unroll
            for (int n = 0; n < 4; ++n)
                acc[m][n] = __builtin_amdgcn_mfma_f32_16x16x32_bf16(a[m], b[n], acc[m][n], 0, 0, 0);
    }

    float bn3[4];
    #pragma unroll
    for (int n = 0; n < 4; ++n) bn3[n] = b3[wc * 64 + n * 16 + lr];

    __syncthreads();
    unsigned short* m_lds = x_lds;   // overlay [64][ESTRIDE]
    #pragma unroll
    for (int m = 0; m < 2; ++m)
        #pragma unroll
        for (int n = 0; n < 4; ++n)
            #pragma unroll
            for (int j = 0; j < 4; ++j) {
                int row = wr * 32 + m * 16 + lk * 4 + j;
                int col = wc * 64 + n * 16 + lr;
                m_lds[row * ESTRIDE + col] = f2bf(silu_f(acc[m][n][j] + bn3[n]));
            }
    __syncthreads();

    // ---- mm4 ----
    f32x4 acc2[2][4];
    #pragma unroll
    for (int m = 0; m < 2; ++m)
        #pragma unroll
        for (int n = 0; n < 4; ++n) acc2[m][n] = (f32x4){0.f, 0.f, 0.f, 0.f};

    #pragma unroll
    for (int ks = 0; ks < 4; ++ks) {
        bhalf8 a[2], b[4];
        #pragma unroll
        for (int m = 0; m < 2; ++m)
            a[m] = *(const bhalf8*)(&m_lds[(wr * 32 + m * 16 + lr) * ESTRIDE + ks * 32 + lk * 8]);
        #pragma unroll
        for (int n = 0; n < 4; ++n)
            b[n] = *(const bhalf8*)(W4T + (size_t)(wc * 64 + n * 16 + lr) * H + ks * 32 + lk * 8);
        #pragma unroll
        for (int m = 0; m < 2; ++m)
            #pragma unroll
            for (int n = 0; n < 4; ++n)
                acc2[m][n] = __builtin_amdgcn_mfma_f32_16x16x32_bf16(a[m], b[n], acc2[m][n], 0, 0, 0);
    }

    float bn4[4];
    #pragma unroll
    for (int n = 0; n < 4; ++n) bn4[n] = b4[wc * 64 + n * 16 + lr];

    #pragma unroll
    for (int m = 0; m < 2; ++m)
        #pragma unroll
        for (int n = 0; n < 4; ++n)
            #pragma unroll
            for (int j = 0; j < 4; ++j) {
                int row = wr * 32 + m * 16 + lk * 4 + j;
                int col = wc * 64 + n * 16 + lr;
                int node = nb + row;
                if (node < NN) {
                    float base = nf[(size_t)node * H + col];
                    out0[(size_t)node * H + col] = base + silu_f(acc2[m][n][j] + bn4[n]);
                }
            }
}

extern "C" void kernel_launch(void* const* d_in, const int* in_sizes, int n_in,
                              void* d_out, int out_size, void* d_ws, size_t ws_size,
                              hipStream_t stream) {
    const float* nf  = (const float*)d_in[0];
    const float* lat = (const float*)d_in[2];
    const float* fd  = (const float*)d_in[3];
    const float* W1  = (const float*)d_in[4];
    const float* b1  = (const float*)d_in[5];
    const float* W2  = (const float*)d_in[6];
    const float* b2  = (const float*)d_in[7];
    const float* W3  = (const float*)d_in[8];
    const float* b3  = (const float*)d_in[9];
    const float* W4  = (const float*)d_in[10];
    const float* b4  = (const float*)d_in[11];
    const int* ei    = (const int*)d_in[12];
    const int* e2g   = (const int*)d_in[13];

    float* out0     = (float*)d_out;
    float* out_edge = (float*)d_out + (size_t)NN * H;

    char* ws = (char*)d_ws;
    size_t off = 0;
    float* sums = (float*)(ws + off);           off += (size_t)NN * H * 4;   // 25.6 MB
    float* cnt  = (float*)(ws + off);           off += (size_t)NN * 4;       // 0.2 MB
    unsigned short* nfb  = (unsigned short*)(ws + off); off += (size_t)NN * H * 2;  // 12.8 MB
    unsigned short* W1T  = (unsigned short*)(ws + off); off += (size_t)H * K1 * 2;
    unsigned short* W2T  = (unsigned short*)(ws + off); off += (size_t)H * H * 2;
    unsigned short* W3T  = (unsigned short*)(ws + off); off += (size_t)H * K3 * 2;
    unsigned short* W4T  = (unsigned short*)(ws + off); off += (size_t)H * H * 2;
    unsigned short* latg = (unsigned short*)(ws + off); off += (size_t)GG * 16 * 2;

    (void)hipMemsetAsync(sums, 0, (size_t)NN * H * 4 + (size_t)NN * 4, stream);

    cvt_nf_kernel<<<(NN * H / 4 + 255) / 256, 256, 0, stream>>>(nf, nfb);
    transpose_w_kernel<<<dim3(2, H), 256, 0, stream>>>(W1, W1T, 268, K1);
    transpose_w_kernel<<<dim3(1, H), 256, 0, stream>>>(W2, W2T, H, H);
    transpose_w_kernel<<<dim3(1, H), 256, 0, stream>>>(W3, W3T, K3, K3);
    transpose_w_kernel<<<dim3(1, H), 256, 0, stream>>>(W4, W4T, H, H);
    lat_kernel<<<(GG * 16 + 255) / 256, 256, 0, stream>>>(lat, latg);
    count_kernel<<<(EE + 255) / 256, 256, 0, stream>>>(ei, cnt);

    edge_kernel<<<EE / 64, 256, 0, stream>>>(nfb, latg, fd, W1T, b1, W2T, b2,
                                             ei, e2g, out_edge, sums);
    node_kernel<<<(NN + 63) / 64, 256, 0, stream>>>(nf, nfb, sums, cnt, W3T, b3, W4T, b4, out0);
}

// Round 4
// 544.161 us; speedup vs baseline: 3.5915x; 1.0441x over previous
//
#include <hip/hip_runtime.h>
#include <hip/hip_bf16.h>
#include <math.h>

#define H  128
#define NN 50000
#define EE 800000
#define GG 256
#define NB 196          // ceil(NN/256)

#define K1 288          // padded 268 -> 288 (9 k-steps of 32)
#define K3 256
#define XSTRIDE 296     // edge x-tile LDS row stride (bf16 elems)
#define NSTRIDE 264     // node x-tile LDS row stride
#define ESTRIDE 136     // hidden tile LDS row stride

typedef __attribute__((ext_vector_type(8))) short bhalf8;
typedef __attribute__((ext_vector_type(4))) float f32x4;

__device__ __forceinline__ float silu_f(float x) {
    return x / (1.0f + __expf(-x));
}

// fp32 -> bf16 round-to-nearest-even
__device__ __forceinline__ unsigned short f2bf(float x) {
    unsigned int u = __float_as_uint(x);
    unsigned int r = 0x7fffu + ((u >> 16) & 1u);
    return (unsigned short)((u + r) >> 16);
}

// ---- prep kernels ----

__global__ void cvt_nf_kernel(const float* __restrict__ nf, unsigned short* __restrict__ nfb) {
    int idx = blockIdx.x * blockDim.x + threadIdx.x;
    if (idx >= NN * H / 4) return;
    float4 v = *(const float4*)(nf + (size_t)idx * 4);
    ushort4 o;
    o.x = f2bf(v.x); o.y = f2bf(v.y); o.z = f2bf(v.z); o.w = f2bf(v.w);
    *(ushort4*)(nfb + (size_t)idx * 4) = o;
}

__global__ void transpose_w_kernel(const float* __restrict__ W, unsigned short* __restrict__ WT,
                                   int K, int Kpad) {
    int k = blockIdx.x * blockDim.x + threadIdx.x;
    int c = blockIdx.y;
    if (k >= Kpad) return;
    WT[(size_t)c * Kpad + k] = (k < K) ? f2bf(W[(size_t)k * H + c]) : (unsigned short)0;
}

__global__ void lat_kernel(const float* __restrict__ lat, unsigned short* __restrict__ latg) {
    int idx = blockIdx.x * blockDim.x + threadIdx.x;
    if (idx >= GG * 16) return;
    int g = idx >> 4, r = idx & 15;
    float v = 0.0f;
    if (r < 9) {
        int i = r / 3, k = r % 3;
        const float* L = lat + g * 9;
        v = L[i*3+0]*L[k*3+0] + L[i*3+1]*L[k*3+1] + L[i*3+2]*L[k*3+2];
    }
    latg[idx] = f2bf(v);
}

// ---- CSR build ----

__global__ void count_kernel(const int* __restrict__ ei, int* __restrict__ cnt_i) {
    int e = blockIdx.x * blockDim.x + threadIdx.x;
    if (e < EE) atomicAdd(&cnt_i[ei[EE + e]], 1);
}

__global__ void scan1_kernel(const int* __restrict__ cnt_i, int* __restrict__ bsum) {
    __shared__ int red[256];
    int b = blockIdx.x, t = threadIdx.x;
    int n = b * 256 + t;
    red[t] = (n < NN) ? cnt_i[n] : 0;
    __syncthreads();
    for (int s = 128; s > 0; s >>= 1) {
        if (t < s) red[t] += red[t + s];
        __syncthreads();
    }
    if (t == 0) bsum[b] = red[0];
}

__global__ void scan2_kernel(const int* __restrict__ bsum, int* __restrict__ bbase) {
    __shared__ int tmp[256];
    int t = threadIdx.x;
    int c = (t < NB) ? bsum[t] : 0;
    tmp[t] = c;
    __syncthreads();
    for (int s = 1; s < 256; s <<= 1) {
        int u = (t >= s) ? tmp[t - s] : 0;
        __syncthreads();
        tmp[t] += u;
        __syncthreads();
    }
    if (t < NB) bbase[t] = tmp[t] - c;   // exclusive
}

__global__ void scan3_kernel(const int* __restrict__ cnt_i, const int* __restrict__ bbase,
                             int* __restrict__ row_start) {
    __shared__ int tmp[256];
    int b = blockIdx.x, t = threadIdx.x;
    int n = b * 256 + t;
    int c = (n < NN) ? cnt_i[n] : 0;
    tmp[t] = c;
    __syncthreads();
    for (int s = 1; s < 256; s <<= 1) {
        int u = (t >= s) ? tmp[t - s] : 0;
        __syncthreads();
        tmp[t] += u;
        __syncthreads();
    }
    if (n < NN) row_start[n] = bbase[b] + tmp[t] - c;   // exclusive
}

__global__ void scatter_kernel(const int* __restrict__ ei, const int* __restrict__ row_start,
                               int* __restrict__ fill, int* __restrict__ eidx) {
    int e = blockIdx.x * blockDim.x + threadIdx.x;
    if (e < EE) {
        int d = ei[EE + e];
        int pos = row_start[d] + atomicAdd(&fill[d], 1);
        eidx[pos] = e;
    }
}

// ---- edge kernel: 64 edges x 128 cols per block, 4 waves (2x2) ----
__global__ __launch_bounds__(256) void edge_kernel(
    const unsigned short* __restrict__ nfb, const unsigned short* __restrict__ latg,
    const float* __restrict__ fd,
    const unsigned short* __restrict__ W1T, const float* __restrict__ b1,
    const unsigned short* __restrict__ W2T, const float* __restrict__ b2,
    const int* __restrict__ ei, const int* __restrict__ e2g,
    float* __restrict__ out_edge)
{
    __shared__ unsigned short x_lds[64 * XSTRIDE];   // 37.9 KB; overlaid as e1[64][ESTRIDE]
    __shared__ int sSrc[64], sDst[64], sG[64];

    int tid = threadIdx.x;
    int eb = blockIdx.x * 64;

    if (tid < 64)       sSrc[tid]       = ei[eb + tid];
    else if (tid < 128) sDst[tid - 64]  = ei[EE + eb + (tid - 64)];
    else if (tid < 192) sG[tid - 128]   = e2g[eb + (tid - 128)];
    __syncthreads();

    // stage hi|hj: 64 rows x 32 chunks of 8 bf16 (cols 0..255)
    #pragma unroll
    for (int p = 0; p < 8; ++p) {
        int idx = p * 256 + tid;
        int e = idx >> 5, c = idx & 31;
        int node = (c < 16) ? sSrc[e] : sDst[e];
        int cc = c & 15;
        uint4 v = *(const uint4*)(nfb + (size_t)node * H + cc * 8);
        *(uint4*)(&x_lds[e * XSTRIDE + c * 8]) = v;
    }
    // tail cols 256..287: lat(9) fd(3) zeros(20)
    if (tid < 64) {
        int e = tid, g = sG[e];
        unsigned short t[16];
        #pragma unroll
        for (int q = 0; q < 9; ++q) t[q] = latg[g * 16 + q];
        #pragma unroll
        for (int q = 0; q < 3; ++q) t[9 + q] = f2bf(fd[(size_t)(eb + e) * 3 + q]);
        #pragma unroll
        for (int q = 12; q < 16; ++q) t[q] = 0;
        *(uint4*)(&x_lds[e * XSTRIDE + 256]) = ((uint4*)t)[0];
        *(uint4*)(&x_lds[e * XSTRIDE + 264]) = ((uint4*)t)[1];
        uint4 z; z.x = z.y = z.z = z.w = 0;
        *(uint4*)(&x_lds[e * XSTRIDE + 272]) = z;
        *(uint4*)(&x_lds[e * XSTRIDE + 280]) = z;
    }
    __syncthreads();

    int wid = tid >> 6, lane = tid & 63;
    int wr = wid >> 1, wc = wid & 1;
    int lr = lane & 15, lk = lane >> 4;

    // ---- mm1: x[64,288] @ W1T -> e1 ----
    f32x4 acc[2][4];
    #pragma unroll
    for (int m = 0; m < 2; ++m)
        #pragma unroll
        for (int n = 0; n < 4; ++n) acc[m][n] = (f32x4){0.f, 0.f, 0.f, 0.f};

    for (int ks = 0; ks < 9; ++ks) {
        bhalf8 a[2], b[4];
        #pragma unroll
        for (int m = 0; m < 2; ++m)
            a[m] = *(const bhalf8*)(&x_lds[(wr * 32 + m * 16 + lr) * XSTRIDE + ks * 32 + lk * 8]);
        #pragma unroll
        for (int n = 0; n < 4; ++n)
            b[n] = *(const bhalf8*)(W1T + (size_t)(wc * 64 + n * 16 + lr) * K1 + ks * 32 + lk * 8);
        #pragma unroll
        for (int m = 0; m < 2; ++m)
            #pragma unroll
            for (int n = 0; n < 4; ++n)
                acc[m][n] = __builtin_amdgcn_mfma_f32_16x16x32_bf16(a[m], b[n], acc[m][n], 0, 0, 0);
    }

    float bn1[4];
    #pragma unroll
    for (int n = 0; n < 4; ++n) bn1[n] = b1[wc * 64 + n * 16 + lr];

    __syncthreads();
    unsigned short* e1 = x_lds;   // overlay [64][ESTRIDE]
    #pragma unroll
    for (int m = 0; m < 2; ++m)
        #pragma unroll
        for (int n = 0; n < 4; ++n)
            #pragma unroll
            for (int j = 0; j < 4; ++j) {
                int row = wr * 32 + m * 16 + lk * 4 + j;
                int col = wc * 64 + n * 16 + lr;
                e1[row * ESTRIDE + col] = f2bf(silu_f(acc[m][n][j] + bn1[n]));
            }
    __syncthreads();

    // ---- mm2: e1[64,128] @ W2T ----
    f32x4 acc2[2][4];
    #pragma unroll
    for (int m = 0; m < 2; ++m)
        #pragma unroll
        for (int n = 0; n < 4; ++n) acc2[m][n] = (f32x4){0.f, 0.f, 0.f, 0.f};

    #pragma unroll
    for (int ks = 0; ks < 4; ++ks) {
        bhalf8 a[2], b[4];
        #pragma unroll
        for (int m = 0; m < 2; ++m)
            a[m] = *(const bhalf8*)(&e1[(wr * 32 + m * 16 + lr) * ESTRIDE + ks * 32 + lk * 8]);
        #pragma unroll
        for (int n = 0; n < 4; ++n)
            b[n] = *(const bhalf8*)(W2T + (size_t)(wc * 64 + n * 16 + lr) * H + ks * 32 + lk * 8);
        #pragma unroll
        for (int m = 0; m < 2; ++m)
            #pragma unroll
            for (int n = 0; n < 4; ++n)
                acc2[m][n] = __builtin_amdgcn_mfma_f32_16x16x32_bf16(a[m], b[n], acc2[m][n], 0, 0, 0);
    }

    float bn2[4];
    #pragma unroll
    for (int n = 0; n < 4; ++n) bn2[n] = b2[wc * 64 + n * 16 + lr];

    #pragma unroll
    for (int m = 0; m < 2; ++m)
        #pragma unroll
        for (int n = 0; n < 4; ++n)
            #pragma unroll
            for (int j = 0; j < 4; ++j) {
                int row = wr * 32 + m * 16 + lk * 4 + j;
                int col = wc * 64 + n * 16 + lr;
                out_edge[(size_t)(eb + row) * H + col] = silu_f(acc2[m][n][j] + bn2[n]);
            }
}

// ---- gather-mean: one wave per node ----
__global__ __launch_bounds__(256) void agg_kernel(
    const float* __restrict__ out_edge, const int* __restrict__ row_start,
    const int* __restrict__ cnt_i, const int* __restrict__ eidx,
    float* __restrict__ agg)
{
    int wid = threadIdx.x >> 6, lane = threadIdx.x & 63;
    int n = blockIdx.x * 4 + wid;
    if (n >= NN) return;
    int start = row_start[n], deg = cnt_i[n];
    float ax = 0.f, ay = 0.f;
    int i = 0;
    for (; i + 2 <= deg; i += 2) {
        int e0 = eidx[start + i], e1 = eidx[start + i + 1];
        float2 v0 = *(const float2*)(out_edge + (size_t)e0 * H + lane * 2);
        float2 v1 = *(const float2*)(out_edge + (size_t)e1 * H + lane * 2);
        ax += v0.x + v1.x; ay += v0.y + v1.y;
    }
    if (i < deg) {
        int e0 = eidx[start + i];
        float2 v0 = *(const float2*)(out_edge + (size_t)e0 * H + lane * 2);
        ax += v0.x; ay += v0.y;
    }
    float inv = 1.0f / fmaxf((float)deg, 1.0f);
    *(float2*)(agg + (size_t)n * H + lane * 2) = make_float2(ax * inv, ay * inv);
}

// ---- node kernel ----
__global__ __launch_bounds__(256) void node_kernel(
    const float* __restrict__ nf, const unsigned short* __restrict__ nfb,
    const float* __restrict__ agg,
    const unsigned short* __restrict__ W3T, const float* __restrict__ b3,
    const unsigned short* __restrict__ W4T, const float* __restrict__ b4,
    float* __restrict__ out0)
{
    __shared__ unsigned short x_lds[64 * NSTRIDE];
    int tid = threadIdx.x;
    int nb = blockIdx.x * 64;

    #pragma unroll
    for (int p = 0; p < 4; ++p) {
        int idx = p * 256 + tid;
        int n = idx >> 4, c = idx & 15;
        int node = nb + n; if (node >= NN) node = NN - 1;
        uint4 v = *(const uint4*)(nfb + (size_t)node * H + c * 8);
        *(uint4*)(&x_lds[n * NSTRIDE + c * 8]) = v;
    }
    #pragma unroll
    for (int p = 0; p < 8; ++p) {
        int idx = p * 256 + tid;
        int n = idx >> 5, c = idx & 31;
        int node = nb + n; if (node >= NN) node = NN - 1;
        float4 s = *(const float4*)(agg + (size_t)node * H + c * 4);
        ushort4 o;
        o.x = f2bf(s.x); o.y = f2bf(s.y); o.z = f2bf(s.z); o.w = f2bf(s.w);
        *(ushort4*)(&x_lds[n * NSTRIDE + 128 + c * 4]) = o;
    }
    __syncthreads();

    int wid = tid >> 6, lane = tid & 63;
    int wr = wid >> 1, wc = wid & 1;
    int lr = lane & 15, lk = lane >> 4;

    f32x4 acc[2][4];
    #pragma unroll
    for (int m = 0; m < 2; ++m)
        #pragma unroll
        for (int n = 0; n < 4; ++n) acc[m][n] = (f32x4){0.f, 0.f, 0.f, 0.f};

    #pragma unroll
    for (int ks = 0; ks < 8; ++ks) {
        bhalf8 a[2], b[4];
        #pragma unroll
        for (int m = 0; m < 2; ++m)
            a[m] = *(const bhalf8*)(&x_lds[(wr * 32 + m * 16 + lr) * NSTRIDE + ks * 32 + lk * 8]);
        #pragma unroll
        for (int n = 0; n < 4; ++n)
            b[n] = *(const bhalf8*)(W3T + (size_t)(wc * 64 + n * 16 + lr) * K3 + ks * 32 + lk * 8);
        #pragma unroll
        for (int m = 0; m < 2; ++m)
            #pragma unroll
            for (int n = 0; n < 4; ++n)
                acc[m][n] = __builtin_amdgcn_mfma_f32_16x16x32_bf16(a[m], b[n], acc[m][n], 0, 0, 0);
    }

    float bn3[4];
    #pragma unroll
    for (int n = 0; n < 4; ++n) bn3[n] = b3[wc * 64 + n * 16 + lr];

    __syncthreads();
    unsigned short* m_lds = x_lds;
    #pragma unroll
    for (int m = 0; m < 2; ++m)
        #pragma unroll
        for (int n = 0; n < 4; ++n)
            #pragma unroll
            for (int j = 0; j < 4; ++j) {
                int row = wr * 32 + m * 16 + lk * 4 + j;
                int col = wc * 64 + n * 16 + lr;
                m_lds[row * ESTRIDE + col] = f2bf(silu_f(acc[m][n][j] + bn3[n]));
            }
    __syncthreads();

    f32x4 acc2[2][4];
    #pragma unroll
    for (int m = 0; m < 2; ++m)
        #pragma unroll
        for (int n = 0; n < 4; ++n) acc2[m][n] = (f32x4){0.f, 0.f, 0.f, 0.f};

    #pragma unroll
    for (int ks = 0; ks < 4; ++ks) {
        bhalf8 a[2], b[4];
        #pragma unroll
        for (int m = 0; m < 2; ++m)
            a[m] = *(const bhalf8*)(&m_lds[(wr * 32 + m * 16 + lr) * ESTRIDE + ks * 32 + lk * 8]);
        #pragma unroll
        for (int n = 0; n < 4; ++n)
            b[n] = *(const bhalf8*)(W4T + (size_t)(wc * 64 + n * 16 + lr) * H + ks * 32 + lk * 8);
        #pragma unroll
        for (int m = 0; m < 2; ++m)
            #pragma unroll
            for (int n = 0; n < 4; ++n)
                acc2[m][n] = __builtin_amdgcn_mfma_f32_16x16x32_bf16(a[m], b[n], acc2[m][n], 0, 0, 0);
    }

    float bn4[4];
    #pragma unroll
    for (int n = 0; n < 4; ++n) bn4[n] = b4[wc * 64 + n * 16 + lr];

    #pragma unroll
    for (int m = 0; m < 2; ++m)
        #pragma unroll
        for (int n = 0; n < 4; ++n)
            #pragma unroll
            for (int j = 0; j < 4; ++j) {
                int row = wr * 32 + m * 16 + lk * 4 + j;
                int col = wc * 64 + n * 16 + lr;
                int node = nb + row;
                if (node < NN) {
                    float base = nf[(size_t)node * H + col];
                    out0[(size_t)node * H + col] = base + silu_f(acc2[m][n][j] + bn4[n]);
                }
            }
}

extern "C" void kernel_launch(void* const* d_in, const int* in_sizes, int n_in,
                              void* d_out, int out_size, void* d_ws, size_t ws_size,
                              hipStream_t stream) {
    const float* nf  = (const float*)d_in[0];
    const float* lat = (const float*)d_in[2];
    const float* fd  = (const float*)d_in[3];
    const float* W1  = (const float*)d_in[4];
    const float* b1  = (const float*)d_in[5];
    const float* W2  = (const float*)d_in[6];
    const float* b2  = (const float*)d_in[7];
    const float* W3  = (const float*)d_in[8];
    const float* b3  = (const float*)d_in[9];
    const float* W4  = (const float*)d_in[10];
    const float* b4  = (const float*)d_in[11];
    const int* ei    = (const int*)d_in[12];
    const int* e2g   = (const int*)d_in[13];

    float* out0     = (float*)d_out;
    float* out_edge = (float*)d_out + (size_t)NN * H;

    char* ws = (char*)d_ws;
    size_t off = 0;
    float* agg = (float*)(ws + off);                    off += (size_t)NN * H * 4;     // 25.6 MB
    int* cnt_i      = (int*)(ws + off);                 off += (size_t)NB * 256 * 4;   // zeroed together
    int* fill       = (int*)(ws + off);                 off += (size_t)NB * 256 * 4;   // with cnt_i
    int* row_start  = (int*)(ws + off);                 off += (size_t)NB * 256 * 4;
    int* bsum       = (int*)(ws + off);                 off += 256 * 4;
    int* bbase      = (int*)(ws + off);                 off += 256 * 4;
    int* eidx       = (int*)(ws + off);                 off += (size_t)EE * 4;         // 3.2 MB
    unsigned short* nfb  = (unsigned short*)(ws + off); off += (size_t)NN * H * 2;     // 12.8 MB
    unsigned short* W1T  = (unsigned short*)(ws + off); off += (size_t)H * K1 * 2;
    unsigned short* W2T  = (unsigned short*)(ws + off); off += (size_t)H * H * 2;
    unsigned short* W3T  = (unsigned short*)(ws + off); off += (size_t)H * K3 * 2;
    unsigned short* W4T  = (unsigned short*)(ws + off); off += (size_t)H * H * 2;
    unsigned short* latg = (unsigned short*)(ws + off); off += (size_t)GG * 16 * 2;

    // zero cnt_i + fill (adjacent)
    (void)hipMemsetAsync(cnt_i, 0, (size_t)NB * 256 * 4 * 2, stream);

    cvt_nf_kernel<<<(NN * H / 4 + 255) / 256, 256, 0, stream>>>(nf, nfb);
    transpose_w_kernel<<<dim3(2, H), 256, 0, stream>>>(W1, W1T, 268, K1);
    transpose_w_kernel<<<dim3(1, H), 256, 0, stream>>>(W2, W2T, H, H);
    transpose_w_kernel<<<dim3(1, H), 256, 0, stream>>>(W3, W3T, K3, K3);
    transpose_w_kernel<<<dim3(1, H), 256, 0, stream>>>(W4, W4T, H, H);
    lat_kernel<<<(GG * 16 + 255) / 256, 256, 0, stream>>>(lat, latg);

    // CSR build
    count_kernel<<<(EE + 255) / 256, 256, 0, stream>>>(ei, cnt_i);
    scan1_kernel<<<NB, 256, 0, stream>>>(cnt_i, bsum);
    scan2_kernel<<<1, 256, 0, stream>>>(bsum, bbase);
    scan3_kernel<<<NB, 256, 0, stream>>>(cnt_i, bbase, row_start);
    scatter_kernel<<<(EE + 255) / 256, 256, 0, stream>>>(ei, row_start, fill, eidx);

    edge_kernel<<<EE / 64, 256, 0, stream>>>(nfb, latg, fd, W1T, b1, W2T, b2,
                                             ei, e2g, out_edge);
    agg_kernel<<<(NN + 3) / 4, 256, 0, stream>>>(out_edge, row_start, cnt_i, eidx, agg);
    node_kernel<<<(NN + 63) / 64, 256, 0, stream>>>(nf, nfb, agg, W3T, b3, W4T, b4, out0);
}